// Round 16
// baseline (503.350 us; speedup 1.0000x reference)
//
#include <hip/hip_runtime.h>
#include <math.h>

typedef short bf16x8 __attribute__((ext_vector_type(8)));
typedef float f32x4 __attribute__((ext_vector_type(4)));
typedef unsigned uint4n __attribute__((ext_vector_type(4)));

// ---------- bf16 pack/unpack helpers (k in low16, v in high16) ----------
__device__ __forceinline__ unsigned bfr_(float f) {
    unsigned u = __float_as_uint(f);
    return (u + 0x7fffu + ((u >> 16) & 1u)) >> 16;
}
__device__ __forceinline__ unsigned pack2_(float lo, float hi) {
    return bfr_(lo) | (bfr_(hi) << 16);
}
__device__ __forceinline__ float unlo_(unsigned u) { return __uint_as_float(u << 16); }
__device__ __forceinline__ float unhi_(unsigned u) { return __uint_as_float(u & 0xffff0000u); }
__device__ __forceinline__ float bf2f_(unsigned short us) {
    return __uint_as_float((unsigned)us << 16);
}

// ---------------- CSR build ----------------
__global__ void k_hist(const int* __restrict__ dst, int* __restrict__ deg, int E) {
    int e = blockIdx.x * 256 + threadIdx.x;
    if (e < E) atomicAdd(&deg[dst[e]], 1);
}

__global__ void k_scan1(const int* __restrict__ deg, int* __restrict__ rp,
                        int* __restrict__ bsum, int n) {
    __shared__ int sh[256];
    int t = threadIdx.x;
    int base = blockIdx.x * 1024 + t * 4;
    int v0 = (base + 0 < n) ? deg[base + 0] : 0;
    int v1 = (base + 1 < n) ? deg[base + 1] : 0;
    int v2 = (base + 2 < n) ? deg[base + 2] : 0;
    int v3 = (base + 3 < n) ? deg[base + 3] : 0;
    int ts = v0 + v1 + v2 + v3;
    sh[t] = ts;
    __syncthreads();
    for (int off = 1; off < 256; off <<= 1) {
        int x = (t >= off) ? sh[t - off] : 0;
        __syncthreads();
        sh[t] += x;
        __syncthreads();
    }
    int run = sh[t] - ts;
    if (base + 0 < n) rp[base + 0] = run;
    run += v0;
    if (base + 1 < n) rp[base + 1] = run;
    run += v1;
    if (base + 2 < n) rp[base + 2] = run;
    run += v2;
    if (base + 3 < n) rp[base + 3] = run;
    if (t == 255) bsum[blockIdx.x] = sh[255];
}

__global__ void k_scan2(int* __restrict__ bsum, int nb) {
    __shared__ int sh[256];
    int t = threadIdx.x;
    int v = (t < nb) ? bsum[t] : 0;
    sh[t] = v;
    __syncthreads();
    for (int off = 1; off < 256; off <<= 1) {
        int x = (t >= off) ? sh[t - off] : 0;
        __syncthreads();
        sh[t] += x;
        __syncthreads();
    }
    if (t < nb) bsum[t] = sh[t] - v;
}

// finalize rp; zero cur (aliased onto deg)
__global__ void k_scan3(int* __restrict__ rp, const int* __restrict__ bsum,
                        int* __restrict__ cur, int n, int total) {
    int t = threadIdx.x;
    int base = blockIdx.x * 1024 + t * 4;
    int add = bsum[blockIdx.x];
    if (base + 0 < n) { rp[base + 0] += add; cur[base + 0] = 0; }
    if (base + 1 < n) { rp[base + 1] += add; cur[base + 1] = 0; }
    if (base + 2 < n) { rp[base + 2] += add; cur[base + 2] = 0; }
    if (base + 3 < n) { rp[base + 3] += add; cur[base + 3] = 0; }
    if (blockIdx.x == 0 && t == 0) rp[n] = total;
}

// single-pass scatter: CSR-ordered src_perm (4B) + bf16 eap (16B) at pos.
// NT stores: lines written once, read much later -> bypass temporal caching.
__global__ void k_scatter(const int* __restrict__ src, const int* __restrict__ dst,
                          const int* __restrict__ rp, int* __restrict__ cur,
                          const float4* __restrict__ ea, int* __restrict__ src_perm,
                          uint4n* __restrict__ eap, int E) {
    int e = blockIdx.x * 256 + threadIdx.x;
    if (e >= E) return;
    float4 a = ea[(size_t)e * 2 + 0];
    float4 b = ea[(size_t)e * 2 + 1];
    uint4n u;
    u.x = pack2_(a.x, a.y);
    u.y = pack2_(a.z, a.w);
    u.z = pack2_(b.x, b.y);
    u.w = pack2_(b.z, b.w);
    int d = dst[e];
    int pos = rp[d] + atomicAdd(&cur[d], 1);
    __builtin_nontemporal_store(src[e], &src_perm[pos]);
    __builtin_nontemporal_store(u, &eap[pos]);
}

// ---------------- W prep: pack [Wq|Wk|Wv|Ws] transposed bf16 [160][136] ------------
__global__ void k_wprep(const float* __restrict__ Wq, const float* __restrict__ Wk,
                        const float* __restrict__ Wv, const float* __restrict__ Ws,
                        short* __restrict__ wpackT) {
    int i = blockIdx.x * 256 + threadIdx.x;
    if (i >= 160 * 136) return;
    int c = i / 136, k = i % 136;
    short v = 0;
    if (k < 128) {
        const float* W = c < 40 ? Wq : c < 80 ? Wk : c < 120 ? Wv : Ws;
        v = (short)bfr_(W[k * 40 + (c % 40)]);
    }
    wpackT[i] = v;
}

// ---------------- MFMA projection layer 1 ----------------
// outputs: q bf16 [N][4][16] (line-aligned head rows), kv packed [N][4][16], s bf16
__global__ __launch_bounds__(256) void k_proj1m(
    const float* __restrict__ X, const short* __restrict__ wpackT,
    const float* __restrict__ bq, const float* __restrict__ bk,
    const float* __restrict__ bv, const float* __restrict__ bs,
    unsigned short* __restrict__ qO, unsigned* __restrict__ kvO,
    unsigned short* __restrict__ sO, int N) {
    __shared__ short xs[64 * 136];   // 17408 B
    __shared__ short wt[160 * 136];  // 43520 B (reused as C staging f32[64][160])
    int t = threadIdx.x;
    int nb = blockIdx.x * 64;
    for (int i = t; i < 64 * 32; i += 256) {
        int nl = i >> 5, k4 = (i & 31) * 4;
        int node = nb + nl;
        float4 val = make_float4(0.f, 0.f, 0.f, 0.f);
        if (node < N) val = *(const float4*)(X + (size_t)node * 128 + k4);
        uint2 pk;
        pk.x = pack2_(val.x, val.y);
        pk.y = pack2_(val.z, val.w);
        *(uint2*)(xs + nl * 136 + k4) = pk;
    }
    {
        const uint4* wsrc = (const uint4*)wpackT;
        uint4* wdst = (uint4*)wt;
        for (int i = t; i < 2720; i += 256) wdst[i] = wsrc[i];
    }
    __syncthreads();
    int wv = t >> 6;
    int lane = t & 63;
    int lrow = lane & 15;
    int kgrp = lane >> 4;
    bf16x8 afr[4];
    const short* xbase = xs + (wv * 16 + lrow) * 136;
#pragma unroll
    for (int kk = 0; kk < 4; ++kk)
        afr[kk] = *(const bf16x8*)(xbase + kk * 32 + kgrp * 8);
    f32x4 acc[10];
#pragma unroll
    for (int nt = 0; nt < 10; ++nt) acc[nt] = (f32x4){0.f, 0.f, 0.f, 0.f};
#pragma unroll
    for (int nt = 0; nt < 10; ++nt) {
        const short* wbase = wt + (nt * 16 + lrow) * 136;
#pragma unroll
        for (int kk = 0; kk < 4; ++kk) {
            bf16x8 bfr8 = *(const bf16x8*)(wbase + kk * 32 + kgrp * 8);
            acc[nt] = __builtin_amdgcn_mfma_f32_16x16x32_bf16(afr[kk], bfr8, acc[nt],
                                                              0, 0, 0);
        }
    }
    __syncthreads();
    float* cs = (float*)wt;  // [64][160] f32 = 40960 B, fits
#pragma unroll
    for (int nt = 0; nt < 10; ++nt)
#pragma unroll
        for (int r = 0; r < 4; ++r)
            cs[(wv * 16 + kgrp * 4 + r) * 160 + nt * 16 + lrow] = acc[nt][r];
    __syncthreads();
    for (int i = t; i < 64 * 40; i += 256) {
        int nl = i / 40, c = i % 40;
        int node = nb + nl;
        if (node < N) {
            const float* row = cs + nl * 160;
            int hh = c / 10, cc = c % 10;
            float qv = row[c] + bq[c];
            float kf = row[40 + c] + bk[c];
            float vf = row[80 + c] + bv[c];
            float sv = row[120 + c] + bs[c];
            qO[(size_t)node * 64 + hh * 16 + cc] = (unsigned short)bfr_(qv);
            kvO[(size_t)node * 64 + hh * 16 + cc] = pack2_(kf, vf);
            sO[(size_t)node * 40 + c] = (unsigned short)bfr_(sv);
        }
    }
}

// ---------------- VALU projection (layer 2): q bf16, kv packed, s bf16 -------------
template <int FIN, int CH, int KTILE, int NPT, int KVP, int QP, int NPB>
__global__ __launch_bounds__(256) void k_proj(
    const float* __restrict__ X,
    const float* __restrict__ Wq, const float* __restrict__ Wk,
    const float* __restrict__ Wv, const float* __restrict__ Ws,
    const float* __restrict__ bq, const float* __restrict__ bk,
    const float* __restrict__ bv, const float* __restrict__ bs,
    unsigned short* __restrict__ qO, unsigned* __restrict__ kvO,
    unsigned short* __restrict__ sO, int N) {
    constexpr int FOUT = 4 * CH;
    constexpr int COLS = 4 * FOUT;
    constexpr int NCG = COLS / 10;
    constexpr int NG = 256 / NCG;
    static_assert(NG * NPT == NPB, "geometry");
    constexpr int F4 = FIN / 4;
    __shared__ float xs[FIN * NPB];
    __shared__ float wbuf[KTILE * COLS];
    int t = threadIdx.x;
    int nb = blockIdx.x * NPB;
    for (int i = t; i < NPB * F4; i += 256) {
        int nl = i % NPB;
        int k4 = (i / NPB) * 4;
        int node = nb + nl;
        float4 val = make_float4(0.f, 0.f, 0.f, 0.f);
        if (node < N) val = *(const float4*)(X + (size_t)node * FIN + k4);
        xs[(k4 + 0) * NPB + nl] = val.x;
        xs[(k4 + 1) * NPB + nl] = val.y;
        xs[(k4 + 2) * NPB + nl] = val.z;
        xs[(k4 + 3) * NPB + nl] = val.w;
    }
    int cg = t % NCG, ng = t / NCG;
    int which = (cg * 10) / FOUT, cc0 = (cg * 10) % FOUT;
    float acc[NPT][10];
#pragma unroll
    for (int i = 0; i < NPT; ++i)
#pragma unroll
        for (int j = 0; j < 10; ++j) acc[i][j] = 0.f;

    for (int kt = 0; kt < FIN; kt += KTILE) {
        __syncthreads();
        for (int i = t; i < KTILE * (COLS / 4); i += 256) {
            int kk = i / (COLS / 4);
            int c4 = (i % (COLS / 4)) * 4;
            int wh = c4 / FOUT, cc = c4 % FOUT;
            const float* Wsrc = wh == 0 ? Wq : wh == 1 ? Wk : wh == 2 ? Wv : Ws;
            float4 wv = *(const float4*)(Wsrc + (size_t)(kt + kk) * FOUT + cc);
            wbuf[kk * COLS + c4 + 0] = wv.x;
            wbuf[kk * COLS + c4 + 1] = wv.y;
            wbuf[kk * COLS + c4 + 2] = wv.z;
            wbuf[kk * COLS + c4 + 3] = wv.w;
        }
        __syncthreads();
#pragma unroll 4
        for (int kk = 0; kk < KTILE; ++kk) {
            float xv[NPT];
            if constexpr (NPT == 4) {
                float4 x4 = *(const float4*)(xs + (kt + kk) * NPB + ng * 4);
                xv[0] = x4.x; xv[1] = x4.y; xv[2] = x4.z; xv[3] = x4.w;
            } else if constexpr (NPT == 2) {
                float2 x2 = *(const float2*)(xs + (kt + kk) * NPB + ng * 2);
                xv[0] = x2.x; xv[1] = x2.y;
            } else {
                xv[0] = xs[(kt + kk) * NPB + ng];
            }
            const float2* wp = (const float2*)(wbuf + kk * COLS + cg * 10);
            float wv[10];
#pragma unroll
            for (int jj = 0; jj < 5; ++jj) {
                float2 w2 = wp[jj];
                wv[2 * jj] = w2.x;
                wv[2 * jj + 1] = w2.y;
            }
#pragma unroll
            for (int i = 0; i < NPT; ++i)
#pragma unroll
                for (int j = 0; j < 10; ++j) acc[i][j] += xv[i] * wv[j];
        }
    }
    const float* B = which == 0 ? bq : which == 1 ? bk : which == 2 ? bv : bs;
    float bias[10];
#pragma unroll
    for (int j = 0; j < 10; ++j) bias[j] = B[cc0 + j];
    __syncthreads();
    if (which == 0) {
#pragma unroll
        for (int i = 0; i < NPT; ++i) {
            int node = nb + ng * NPT + i;
            if (node < N)
#pragma unroll
                for (int j = 0; j < 10; ++j) {
                    int col = cc0 + j, hh = col / CH, cc = col % CH;
                    qO[(size_t)node * 4 * QP + hh * QP + cc] =
                        (unsigned short)bfr_(acc[i][j] + bias[j]);
                }
        }
    } else if (which == 3) {
#pragma unroll
        for (int i = 0; i < NPT; ++i) {
            int node = nb + ng * NPT + i;
            if (node < N)
#pragma unroll
                for (int j = 0; j < 10; ++j)
                    sO[(size_t)node * FOUT + cc0 + j] =
                        (unsigned short)bfr_(acc[i][j] + bias[j]);
        }
    } else if (which == 1) {
#pragma unroll
        for (int i = 0; i < NPT; ++i) {
            int nl = ng * NPT + i;
#pragma unroll
            for (int j = 0; j < 10; ++j) wbuf[nl * FOUT + cc0 + j] = acc[i][j] + bias[j];
        }
    }
    __syncthreads();
    if (which == 2) {
#pragma unroll
        for (int i = 0; i < NPT; ++i) {
            int nl = ng * NPT + i;
            int node = nb + nl;
            if (node < N)
#pragma unroll
                for (int j = 0; j < 10; ++j) {
                    int col = cc0 + j, hh = col / CH, cc = col % CH;
                    float kf = wbuf[nl * FOUT + cc0 + j];
                    kvO[(size_t)node * 4 * KVP + hh * KVP + cc] =
                        pack2_(kf, acc[i][j] + bias[j]);
                }
        }
    }
}

// ---------------- fused TransformerConv: 16 lanes per node ----------------
// lane = 16*(node%4)+4*qtr+h; line-aligned kv/q head rows (no straddle).
template <int CH, int KVP, int QP>
__global__ __launch_bounds__(256) void k_conv(
    const int* __restrict__ rp, const int* __restrict__ src_perm,
    const uint4* __restrict__ eap, const float* __restrict__ We,
    const unsigned short* __restrict__ qbf, const unsigned* __restrict__ kv,
    const unsigned short* __restrict__ skp, float* __restrict__ hout,
    float inv_sqrt, int N) {
    constexpr int D = 4 * CH;
    constexpr int NQL = (QP * 2) / 16;  // uint4 loads for q row
    constexpr int NKL = KVP / 4;        // uint4 loads for kv row
    __shared__ float we_s[8 * D];
    for (int i = threadIdx.x; i < 8 * D; i += 256) we_s[i] = We[i];
    __syncthreads();
    int g = blockIdx.x * 256 + threadIdx.x;
    int node = g >> 4;
    int h = g & 3;
    int qtr = (g >> 2) & 3;
    if (node >= N) return;
    int rs = rp[node], re = rp[node + 1];
    unsigned short q16[8 * NQL];
    {
        const uint4* qp = (const uint4*)(qbf + (size_t)node * 4 * QP + h * QP);
#pragma unroll
        for (int i = 0; i < NQL; ++i) *(uint4*)&q16[8 * i] = qp[i];
    }
    float qh[CH];
#pragma unroll
    for (int c = 0; c < CH; ++c) qh[c] = bf2f_(q16[c]);
    float qe[8];
#pragma unroll
    for (int j = 0; j < 8; ++j) {
        float sE = 0.f;
#pragma unroll
        for (int c = 0; c < CH; ++c) sE += qh[c] * we_s[j * D + h * CH + c];
        qe[j] = sE;
    }
    float m = -3.0e38f, l = 0.f;
    float accv[CH] = {};
    float acce[8] = {};
    for (int p = rs + qtr; p < re; p += 4) {
        int sidx = src_perm[p];
        uint4 eu = eap[p];
        float ea8[8];
        ea8[0] = unlo_(eu.x); ea8[1] = unhi_(eu.x);
        ea8[2] = unlo_(eu.y); ea8[3] = unhi_(eu.y);
        ea8[4] = unlo_(eu.z); ea8[5] = unhi_(eu.z);
        ea8[6] = unlo_(eu.w); ea8[7] = unhi_(eu.w);
        unsigned kraw[4 * NKL];
        const uint4* kp = (const uint4*)(kv + (size_t)sidx * 4 * KVP + h * KVP);
#pragma unroll
        for (int i = 0; i < NKL; ++i) *(uint4*)&kraw[4 * i] = kp[i];
        float a = 0.f;
        float vj[CH];
#pragma unroll
        for (int c = 0; c < CH; ++c) {
            unsigned u = kraw[c];
            a += qh[c] * unlo_(u);
            vj[c] = unhi_(u);
        }
#pragma unroll
        for (int j = 0; j < 8; ++j) a += qe[j] * ea8[j];
        a *= inv_sqrt;
        float mn = fmaxf(m, a);
        float so = __expf(m - mn);
        float w = __expf(a - mn);
        l = l * so + w;
#pragma unroll
        for (int c = 0; c < CH; ++c) accv[c] = accv[c] * so + w * vj[c];
#pragma unroll
        for (int j = 0; j < 8; ++j) acce[j] = acce[j] * so + w * ea8[j];
        m = mn;
    }
#pragma unroll
    for (int mask = 4; mask <= 8; mask <<= 1) {
        float mo = __shfl_xor(m, mask);
        float lo = __shfl_xor(l, mask);
        float mn = fmaxf(m, mo);
        float s1 = (m > -1e37f) ? __expf(m - mn) : 0.f;
        float s2 = (mo > -1e37f) ? __expf(mo - mn) : 0.f;
        l = l * s1 + lo * s2;
#pragma unroll
        for (int c = 0; c < CH; ++c) {
            float ao = __shfl_xor(accv[c], mask);
            accv[c] = accv[c] * s1 + ao * s2;
        }
#pragma unroll
        for (int j = 0; j < 8; ++j) {
            float ao = __shfl_xor(acce[j], mask);
            acce[j] = acce[j] * s1 + ao * s2;
        }
        m = mn;
    }
    if (qtr == 0) {
        float inv = 1.0f / (l + 1e-16f);
#pragma unroll
        for (int c = 0; c < CH; ++c) {
            float ec = 0.f;
#pragma unroll
            for (int j = 0; j < 8; ++j) ec += acce[j] * we_s[j * D + h * CH + c];
            float o = (accv[c] + ec) * inv + bf2f_(skp[(size_t)node * D + h * CH + c]);
            hout[(size_t)node * D + h * CH + c] = fmaxf(o, 0.f);
        }
    }
}

// ---------------- pooling (batch is sorted) ----------------
__global__ void k_pool(const float* __restrict__ h2, const int* __restrict__ batch,
                       float* __restrict__ pooled, float* __restrict__ cnt, int N) {
    int t = blockIdx.x * 256 + threadIdx.x;
    int start = t * 16;
    if (start >= N) return;
    int end = min(start + 16, N);
    float acc[20];
#pragma unroll
    for (int c = 0; c < 20; ++c) acc[c] = 0.f;
    int cg = batch[start];
    float run = 0.f;
    for (int n = start; n < end; ++n) {
        int g = batch[n];
        if (g != cg) {
#pragma unroll
            for (int c = 0; c < 20; ++c) atomicAdd(&pooled[cg * 20 + c], acc[c]);
            atomicAdd(&cnt[cg], run);
#pragma unroll
            for (int c = 0; c < 20; ++c) acc[c] = 0.f;
            run = 0.f;
            cg = g;
        }
#pragma unroll
        for (int c = 0; c < 20; ++c) acc[c] += h2[(size_t)n * 20 + c];
        run += 1.f;
    }
#pragma unroll
    for (int c = 0; c < 20; ++c) atomicAdd(&pooled[cg * 20 + c], acc[c]);
    atomicAdd(&cnt[cg], run);
}

__global__ void k_mlp(const float* __restrict__ pooled, const float* __restrict__ cnt,
                      const float* __restrict__ W1, const float* __restrict__ b1,
                      const float* __restrict__ W2, const float* __restrict__ b2,
                      float* __restrict__ out) {
    int g = threadIdx.x;
    if (g >= 64) return;
    float ic = 1.0f / fmaxf(cnt[g], 1.0f);
    float p[20];
#pragma unroll
    for (int i = 0; i < 20; ++i) p[i] = pooled[g * 20 + i] * ic;
    float hid[10];
#pragma unroll
    for (int j = 0; j < 10; ++j) {
        float a = b1[j];
#pragma unroll
        for (int i = 0; i < 20; ++i) a += p[i] * W1[i * 10 + j];
        hid[j] = fmaxf(a, 0.f);
    }
#pragma unroll
    for (int o = 0; o < 3; ++o) {
        float a = b2[o];
#pragma unroll
        for (int j = 0; j < 10; ++j) a += hid[j] * W2[j * 3 + o];
        out[g * 3 + o] = a;
    }
}

extern "C" void kernel_launch(void* const* d_in, const int* in_sizes, int n_in,
                              void* d_out, int out_size, void* d_ws, size_t ws_size,
                              hipStream_t stream) {
    const float* x   = (const float*)d_in[0];
    const int* ei    = (const int*)d_in[1];
    const float* ea  = (const float*)d_in[2];
    const int* batch = (const int*)d_in[3];
    const float *Wq1 = (const float*)d_in[4],  *bq1 = (const float*)d_in[5];
    const float *Wk1 = (const float*)d_in[6],  *bk1 = (const float*)d_in[7];
    const float *Wv1 = (const float*)d_in[8],  *bv1 = (const float*)d_in[9];
    const float *We1 = (const float*)d_in[10];
    const float *Ws1 = (const float*)d_in[11], *bs1 = (const float*)d_in[12];
    const float *Wq2 = (const float*)d_in[13], *bq2 = (const float*)d_in[14];
    const float *Wk2 = (const float*)d_in[15], *bk2 = (const float*)d_in[16];
    const float *Wv2 = (const float*)d_in[17], *bv2 = (const float*)d_in[18];
    const float *We2 = (const float*)d_in[19];
    const float *Ws2 = (const float*)d_in[20], *bs2 = (const float*)d_in[21];
    const float *W1  = (const float*)d_in[22], *b1  = (const float*)d_in[23];
    const float *W2  = (const float*)d_in[24], *b2  = (const float*)d_in[25];

    const int N = in_sizes[0] / 128;  // 100000
    const int E = in_sizes[1] / 2;    // 1600000
    const int* srcI = ei;
    const int* dstI = ei + E;

    // workspace layout (4B units), total ~96 MB
    float* F = (float*)d_ws;
    unsigned short* qbf = (unsigned short*)F;                // [N][4][16] bf16 (3.2M f)
    unsigned*       kv  = (unsigned*)(F + 3200000);          // [N][4][16] (6.4M u)
    float*          h1  = F + 9600000;                       // [N][40] f32 (4M)
    float*          h2  = F + 9600000;                       // alias h1
    unsigned short* s_bf = (unsigned short*)(F + 13600000);  // [N][40] bf16 (2M f)
    uint4*          eap = (uint4*)(F + 15600000);            // E x 16B (6.4M f)
    int*       src_perm = (int*)(F + 22000000);              // E x 4B (1.6M)
    int* I = (int*)(F + 23600000);
    int* deg  = I;                 // N (doubles as cur)
    int* cur  = I;
    int* rpR  = I + 100352;        // N+1
    int* bsum = I + 200704;        // 256
    short* wpackT = (short*)(F + 23900000);  // 160*136 bf16
    float* pooled = F + 23950000;  // 1280
    float* cnt    = pooled + 1280; // 64

    const int SCAN_BLOCKS = (N + 1023) / 1024;
    const int EB = (E + 255) / 256;

    hipMemsetAsync(deg, 0, (size_t)N * 4, stream);
    hipMemsetAsync(pooled, 0, (1280 + 64) * 4, stream);

    // W prep + CSR build (single-pass scatter, NT stores)
    k_wprep<<<(160 * 136 + 255) / 256, 256, 0, stream>>>(Wq1, Wk1, Wv1, Ws1, wpackT);
    k_hist<<<EB, 256, 0, stream>>>(dstI, deg, E);
    k_scan1<<<SCAN_BLOCKS, 256, 0, stream>>>(deg, rpR, bsum, N);
    k_scan2<<<1, 256, 0, stream>>>(bsum, SCAN_BLOCKS);
    k_scan3<<<SCAN_BLOCKS, 256, 0, stream>>>(rpR, bsum, cur, N, E);
    k_scatter<<<EB, 256, 0, stream>>>(srcI, dstI, rpR, cur, (const float4*)ea,
                                      src_perm, (uint4n*)eap, E);

    // layer 1: MFMA projection; conv with line-aligned rows (KVP=QP=16)
    k_proj1m<<<(N + 63) / 64, 256, 0, stream>>>(x, wpackT, bq1, bk1, bv1, bs1,
                                                qbf, kv, s_bf, N);
    k_conv<10, 16, 16><<<(16 * N + 255) / 256, 256, 0, stream>>>(
        rpR, src_perm, eap, We1, qbf, kv, s_bf, h1, 0.31622776601683794f, N);

    // layer 2: 40 -> 4 heads x 5 (KVP=QP=8)
    k_proj<40, 5, 40, 1, 8, 8, 32><<<(N + 31) / 32, 256, 0, stream>>>(
        h1, Wq2, Wk2, Wv2, Ws2, bq2, bk2, bv2, bs2, qbf, kv, s_bf, N);
    k_conv<5, 8, 8><<<(16 * N + 255) / 256, 256, 0, stream>>>(
        rpR, src_perm, eap, We2, qbf, kv, s_bf, h2, 0.4472135954999579f, N);

    // pool + MLP
    k_pool<<<((N + 15) / 16 + 255) / 256, 256, 0, stream>>>(h2, batch, pooled, cnt, N);
    k_mlp<<<1, 64, 0, stream>>>(pooled, cnt, W1, b1, W2, b2, (float*)d_out);
}

// Round 17
// 468.402 us; speedup vs baseline: 1.0746x; 1.0746x over previous
//
#include <hip/hip_runtime.h>
#include <math.h>

typedef short bf16x8 __attribute__((ext_vector_type(8)));
typedef float f32x4 __attribute__((ext_vector_type(4)));

// ---------- bf16 pack/unpack helpers (k in low16, v in high16) ----------
__device__ __forceinline__ unsigned bfr_(float f) {
    unsigned u = __float_as_uint(f);
    return (u + 0x7fffu + ((u >> 16) & 1u)) >> 16;
}
__device__ __forceinline__ unsigned pack2_(float lo, float hi) {
    return bfr_(lo) | (bfr_(hi) << 16);
}
__device__ __forceinline__ float unlo_(unsigned u) { return __uint_as_float(u << 16); }
__device__ __forceinline__ float unhi_(unsigned u) { return __uint_as_float(u & 0xffff0000u); }
__device__ __forceinline__ float bf2f_(unsigned short us) {
    return __uint_as_float((unsigned)us << 16);
}

// ---------------- CSR build ----------------
__global__ void k_hist(const int* __restrict__ dst, int* __restrict__ deg, int E) {
    int e = blockIdx.x * 256 + threadIdx.x;
    if (e < E) atomicAdd(&deg[dst[e]], 1);
}

__global__ void k_scan1(const int* __restrict__ deg, int* __restrict__ rp,
                        int* __restrict__ bsum, int n) {
    __shared__ int sh[256];
    int t = threadIdx.x;
    int base = blockIdx.x * 1024 + t * 4;
    int v0 = (base + 0 < n) ? deg[base + 0] : 0;
    int v1 = (base + 1 < n) ? deg[base + 1] : 0;
    int v2 = (base + 2 < n) ? deg[base + 2] : 0;
    int v3 = (base + 3 < n) ? deg[base + 3] : 0;
    int ts = v0 + v1 + v2 + v3;
    sh[t] = ts;
    __syncthreads();
    for (int off = 1; off < 256; off <<= 1) {
        int x = (t >= off) ? sh[t - off] : 0;
        __syncthreads();
        sh[t] += x;
        __syncthreads();
    }
    int run = sh[t] - ts;
    if (base + 0 < n) rp[base + 0] = run;
    run += v0;
    if (base + 1 < n) rp[base + 1] = run;
    run += v1;
    if (base + 2 < n) rp[base + 2] = run;
    run += v2;
    if (base + 3 < n) rp[base + 3] = run;
    if (t == 255) bsum[blockIdx.x] = sh[255];
}

__global__ void k_scan2(int* __restrict__ bsum, int nb) {
    __shared__ int sh[256];
    int t = threadIdx.x;
    int v = (t < nb) ? bsum[t] : 0;
    sh[t] = v;
    __syncthreads();
    for (int off = 1; off < 256; off <<= 1) {
        int x = (t >= off) ? sh[t - off] : 0;
        __syncthreads();
        sh[t] += x;
        __syncthreads();
    }
    if (t < nb) bsum[t] = sh[t] - v;
}

// finalize rp; zero cur (aliased onto deg)
__global__ void k_scan3(int* __restrict__ rp, const int* __restrict__ bsum,
                        int* __restrict__ cur, int n, int total) {
    int t = threadIdx.x;
    int base = blockIdx.x * 1024 + t * 4;
    int add = bsum[blockIdx.x];
    if (base + 0 < n) { rp[base + 0] += add; cur[base + 0] = 0; }
    if (base + 1 < n) { rp[base + 1] += add; cur[base + 1] = 0; }
    if (base + 2 < n) { rp[base + 2] += add; cur[base + 2] = 0; }
    if (base + 3 < n) { rp[base + 3] += add; cur[base + 3] = 0; }
    if (blockIdx.x == 0 && t == 0) rp[n] = total;
}

// single-pass scatter: CSR-ordered src_perm (4B) + bf16 eap (16B) at pos.
__global__ void k_scatter(const int* __restrict__ src, const int* __restrict__ dst,
                          const int* __restrict__ rp, int* __restrict__ cur,
                          const float4* __restrict__ ea, int* __restrict__ src_perm,
                          uint4* __restrict__ eap, int E) {
    int e = blockIdx.x * 256 + threadIdx.x;
    if (e >= E) return;
    float4 a = ea[(size_t)e * 2 + 0];
    float4 b = ea[(size_t)e * 2 + 1];
    uint4 u;
    u.x = pack2_(a.x, a.y);
    u.y = pack2_(a.z, a.w);
    u.z = pack2_(b.x, b.y);
    u.w = pack2_(b.z, b.w);
    int d = dst[e];
    int pos = rp[d] + atomicAdd(&cur[d], 1);
    src_perm[pos] = src[e];
    eap[pos] = u;
}

// ---------------- W prep: pack [Wq|Wk|Wv|Ws] transposed bf16 [160][136] ------------
__global__ void k_wprep(const float* __restrict__ Wq, const float* __restrict__ Wk,
                        const float* __restrict__ Wv, const float* __restrict__ Ws,
                        short* __restrict__ wpackT) {
    int i = blockIdx.x * 256 + threadIdx.x;
    if (i >= 160 * 136) return;
    int c = i / 136, k = i % 136;
    short v = 0;
    if (k < 128) {
        const float* W = c < 40 ? Wq : c < 80 ? Wk : c < 120 ? Wv : Ws;
        v = (short)bfr_(W[k * 40 + (c % 40)]);
    }
    wpackT[i] = v;
}

// ---------------- MFMA projection layer 1 ----------------
// outputs: q bf16 [N][4][16] (line-aligned head rows), kv packed [N][4][16], s bf16
__global__ __launch_bounds__(256) void k_proj1m(
    const float* __restrict__ X, const short* __restrict__ wpackT,
    const float* __restrict__ bq, const float* __restrict__ bk,
    const float* __restrict__ bv, const float* __restrict__ bs,
    unsigned short* __restrict__ qO, unsigned* __restrict__ kvO,
    unsigned short* __restrict__ sO, int N) {
    __shared__ short xs[64 * 136];   // 17408 B
    __shared__ short wt[160 * 136];  // 43520 B (reused as C staging f32[64][160])
    int t = threadIdx.x;
    int nb = blockIdx.x * 64;
    for (int i = t; i < 64 * 32; i += 256) {
        int nl = i >> 5, k4 = (i & 31) * 4;
        int node = nb + nl;
        float4 val = make_float4(0.f, 0.f, 0.f, 0.f);
        if (node < N) val = *(const float4*)(X + (size_t)node * 128 + k4);
        uint2 pk;
        pk.x = pack2_(val.x, val.y);
        pk.y = pack2_(val.z, val.w);
        *(uint2*)(xs + nl * 136 + k4) = pk;
    }
    {
        const uint4* wsrc = (const uint4*)wpackT;
        uint4* wdst = (uint4*)wt;
        for (int i = t; i < 2720; i += 256) wdst[i] = wsrc[i];
    }
    __syncthreads();
    int wv = t >> 6;
    int lane = t & 63;
    int lrow = lane & 15;
    int kgrp = lane >> 4;
    bf16x8 afr[4];
    const short* xbase = xs + (wv * 16 + lrow) * 136;
#pragma unroll
    for (int kk = 0; kk < 4; ++kk)
        afr[kk] = *(const bf16x8*)(xbase + kk * 32 + kgrp * 8);
    f32x4 acc[10];
#pragma unroll
    for (int nt = 0; nt < 10; ++nt) acc[nt] = (f32x4){0.f, 0.f, 0.f, 0.f};
#pragma unroll
    for (int nt = 0; nt < 10; ++nt) {
        const short* wbase = wt + (nt * 16 + lrow) * 136;
#pragma unroll
        for (int kk = 0; kk < 4; ++kk) {
            bf16x8 bfr8 = *(const bf16x8*)(wbase + kk * 32 + kgrp * 8);
            acc[nt] = __builtin_amdgcn_mfma_f32_16x16x32_bf16(afr[kk], bfr8, acc[nt],
                                                              0, 0, 0);
        }
    }
    __syncthreads();
    float* cs = (float*)wt;  // [64][160] f32 = 40960 B, fits
#pragma unroll
    for (int nt = 0; nt < 10; ++nt)
#pragma unroll
        for (int r = 0; r < 4; ++r)
            cs[(wv * 16 + kgrp * 4 + r) * 160 + nt * 16 + lrow] = acc[nt][r];
    __syncthreads();
    for (int i = t; i < 64 * 40; i += 256) {
        int nl = i / 40, c = i % 40;
        int node = nb + nl;
        if (node < N) {
            const float* row = cs + nl * 160;
            int hh = c / 10, cc = c % 10;
            float qv = row[c] + bq[c];
            float kf = row[40 + c] + bk[c];
            float vf = row[80 + c] + bv[c];
            float sv = row[120 + c] + bs[c];
            qO[(size_t)node * 64 + hh * 16 + cc] = (unsigned short)bfr_(qv);
            kvO[(size_t)node * 64 + hh * 16 + cc] = pack2_(kf, vf);
            sO[(size_t)node * 40 + c] = (unsigned short)bfr_(sv);
        }
    }
}

// ---------------- VALU projection (layer 2): q bf16, kv packed, s bf16 -------------
template <int FIN, int CH, int KTILE, int NPT, int KVP, int QP, int NPB>
__global__ __launch_bounds__(256) void k_proj(
    const float* __restrict__ X,
    const float* __restrict__ Wq, const float* __restrict__ Wk,
    const float* __restrict__ Wv, const float* __restrict__ Ws,
    const float* __restrict__ bq, const float* __restrict__ bk,
    const float* __restrict__ bv, const float* __restrict__ bs,
    unsigned short* __restrict__ qO, unsigned* __restrict__ kvO,
    unsigned short* __restrict__ sO, int N) {
    constexpr int FOUT = 4 * CH;
    constexpr int COLS = 4 * FOUT;
    constexpr int NCG = COLS / 10;
    constexpr int NG = 256 / NCG;
    static_assert(NG * NPT == NPB, "geometry");
    constexpr int F4 = FIN / 4;
    __shared__ float xs[FIN * NPB];
    __shared__ float wbuf[KTILE * COLS];
    int t = threadIdx.x;
    int nb = blockIdx.x * NPB;
    for (int i = t; i < NPB * F4; i += 256) {
        int nl = i % NPB;
        int k4 = (i / NPB) * 4;
        int node = nb + nl;
        float4 val = make_float4(0.f, 0.f, 0.f, 0.f);
        if (node < N) val = *(const float4*)(X + (size_t)node * FIN + k4);
        xs[(k4 + 0) * NPB + nl] = val.x;
        xs[(k4 + 1) * NPB + nl] = val.y;
        xs[(k4 + 2) * NPB + nl] = val.z;
        xs[(k4 + 3) * NPB + nl] = val.w;
    }
    int cg = t % NCG, ng = t / NCG;
    int which = (cg * 10) / FOUT, cc0 = (cg * 10) % FOUT;
    float acc[NPT][10];
#pragma unroll
    for (int i = 0; i < NPT; ++i)
#pragma unroll
        for (int j = 0; j < 10; ++j) acc[i][j] = 0.f;

    for (int kt = 0; kt < FIN; kt += KTILE) {
        __syncthreads();
        for (int i = t; i < KTILE * (COLS / 4); i += 256) {
            int kk = i / (COLS / 4);
            int c4 = (i % (COLS / 4)) * 4;
            int wh = c4 / FOUT, cc = c4 % FOUT;
            const float* Wsrc = wh == 0 ? Wq : wh == 1 ? Wk : wh == 2 ? Wv : Ws;
            float4 wv = *(const float4*)(Wsrc + (size_t)(kt + kk) * FOUT + cc);
            wbuf[kk * COLS + c4 + 0] = wv.x;
            wbuf[kk * COLS + c4 + 1] = wv.y;
            wbuf[kk * COLS + c4 + 2] = wv.z;
            wbuf[kk * COLS + c4 + 3] = wv.w;
        }
        __syncthreads();
#pragma unroll 4
        for (int kk = 0; kk < KTILE; ++kk) {
            float xv[NPT];
            if constexpr (NPT == 4) {
                float4 x4 = *(const float4*)(xs + (kt + kk) * NPB + ng * 4);
                xv[0] = x4.x; xv[1] = x4.y; xv[2] = x4.z; xv[3] = x4.w;
            } else if constexpr (NPT == 2) {
                float2 x2 = *(const float2*)(xs + (kt + kk) * NPB + ng * 2);
                xv[0] = x2.x; xv[1] = x2.y;
            } else {
                xv[0] = xs[(kt + kk) * NPB + ng];
            }
            const float2* wp = (const float2*)(wbuf + kk * COLS + cg * 10);
            float wv[10];
#pragma unroll
            for (int jj = 0; jj < 5; ++jj) {
                float2 w2 = wp[jj];
                wv[2 * jj] = w2.x;
                wv[2 * jj + 1] = w2.y;
            }
#pragma unroll
            for (int i = 0; i < NPT; ++i)
#pragma unroll
                for (int j = 0; j < 10; ++j) acc[i][j] += xv[i] * wv[j];
        }
    }
    const float* B = which == 0 ? bq : which == 1 ? bk : which == 2 ? bv : bs;
    float bias[10];
#pragma unroll
    for (int j = 0; j < 10; ++j) bias[j] = B[cc0 + j];
    __syncthreads();
    if (which == 0) {
#pragma unroll
        for (int i = 0; i < NPT; ++i) {
            int node = nb + ng * NPT + i;
            if (node < N)
#pragma unroll
                for (int j = 0; j < 10; ++j) {
                    int col = cc0 + j, hh = col / CH, cc = col % CH;
                    qO[(size_t)node * 4 * QP + hh * QP + cc] =
                        (unsigned short)bfr_(acc[i][j] + bias[j]);
                }
        }
    } else if (which == 3) {
#pragma unroll
        for (int i = 0; i < NPT; ++i) {
            int node = nb + ng * NPT + i;
            if (node < N)
#pragma unroll
                for (int j = 0; j < 10; ++j)
                    sO[(size_t)node * FOUT + cc0 + j] =
                        (unsigned short)bfr_(acc[i][j] + bias[j]);
        }
    } else if (which == 1) {
#pragma unroll
        for (int i = 0; i < NPT; ++i) {
            int nl = ng * NPT + i;
#pragma unroll
            for (int j = 0; j < 10; ++j) wbuf[nl * FOUT + cc0 + j] = acc[i][j] + bias[j];
        }
    }
    __syncthreads();
    if (which == 2) {
#pragma unroll
        for (int i = 0; i < NPT; ++i) {
            int nl = ng * NPT + i;
            int node = nb + nl;
            if (node < N)
#pragma unroll
                for (int j = 0; j < 10; ++j) {
                    int col = cc0 + j, hh = col / CH, cc = col % CH;
                    float kf = wbuf[nl * FOUT + cc0 + j];
                    kvO[(size_t)node * 4 * KVP + hh * KVP + cc] =
                        pack2_(kf, acc[i][j] + bias[j]);
                }
        }
    }
}

// ---------------- fused TransformerConv: 16 lanes per node ----------------
// lane = 16*(node%4)+4*qtr+h; line-aligned kv/q head rows (no straddle).
template <int CH, int KVP, int QP>
__global__ __launch_bounds__(256) void k_conv(
    const int* __restrict__ rp, const int* __restrict__ src_perm,
    const uint4* __restrict__ eap, const float* __restrict__ We,
    const unsigned short* __restrict__ qbf, const unsigned* __restrict__ kv,
    const unsigned short* __restrict__ skp, float* __restrict__ hout,
    float inv_sqrt, int N) {
    constexpr int D = 4 * CH;
    constexpr int NQL = (QP * 2) / 16;  // uint4 loads for q row
    constexpr int NKL = KVP / 4;        // uint4 loads for kv row
    __shared__ float we_s[8 * D];
    for (int i = threadIdx.x; i < 8 * D; i += 256) we_s[i] = We[i];
    __syncthreads();
    int g = blockIdx.x * 256 + threadIdx.x;
    int node = g >> 4;
    int h = g & 3;
    int qtr = (g >> 2) & 3;
    if (node >= N) return;
    int rs = rp[node], re = rp[node + 1];
    unsigned short q16[8 * NQL];
    {
        const uint4* qp = (const uint4*)(qbf + (size_t)node * 4 * QP + h * QP);
#pragma unroll
        for (int i = 0; i < NQL; ++i) *(uint4*)&q16[8 * i] = qp[i];
    }
    float qh[CH];
#pragma unroll
    for (int c = 0; c < CH; ++c) qh[c] = bf2f_(q16[c]);
    float qe[8];
#pragma unroll
    for (int j = 0; j < 8; ++j) {
        float sE = 0.f;
#pragma unroll
        for (int c = 0; c < CH; ++c) sE += qh[c] * we_s[j * D + h * CH + c];
        qe[j] = sE;
    }
    float m = -3.0e38f, l = 0.f;
    float accv[CH] = {};
    float acce[8] = {};
    for (int p = rs + qtr; p < re; p += 4) {
        int sidx = src_perm[p];
        uint4 eu = eap[p];
        float ea8[8];
        ea8[0] = unlo_(eu.x); ea8[1] = unhi_(eu.x);
        ea8[2] = unlo_(eu.y); ea8[3] = unhi_(eu.y);
        ea8[4] = unlo_(eu.z); ea8[5] = unhi_(eu.z);
        ea8[6] = unlo_(eu.w); ea8[7] = unhi_(eu.w);
        unsigned kraw[4 * NKL];
        const uint4* kp = (const uint4*)(kv + (size_t)sidx * 4 * KVP + h * KVP);
#pragma unroll
        for (int i = 0; i < NKL; ++i) *(uint4*)&kraw[4 * i] = kp[i];
        float a = 0.f;
        float vj[CH];
#pragma unroll
        for (int c = 0; c < CH; ++c) {
            unsigned u = kraw[c];
            a += qh[c] * unlo_(u);
            vj[c] = unhi_(u);
        }
#pragma unroll
        for (int j = 0; j < 8; ++j) a += qe[j] * ea8[j];
        a *= inv_sqrt;
        float mn = fmaxf(m, a);
        float so = __expf(m - mn);
        float w = __expf(a - mn);
        l = l * so + w;
#pragma unroll
        for (int c = 0; c < CH; ++c) accv[c] = accv[c] * so + w * vj[c];
#pragma unroll
        for (int j = 0; j < 8; ++j) acce[j] = acce[j] * so + w * ea8[j];
        m = mn;
    }
#pragma unroll
    for (int mask = 4; mask <= 8; mask <<= 1) {
        float mo = __shfl_xor(m, mask);
        float lo = __shfl_xor(l, mask);
        float mn = fmaxf(m, mo);
        float s1 = (m > -1e37f) ? __expf(m - mn) : 0.f;
        float s2 = (mo > -1e37f) ? __expf(mo - mn) : 0.f;
        l = l * s1 + lo * s2;
#pragma unroll
        for (int c = 0; c < CH; ++c) {
            float ao = __shfl_xor(accv[c], mask);
            accv[c] = accv[c] * s1 + ao * s2;
        }
#pragma unroll
        for (int j = 0; j < 8; ++j) {
            float ao = __shfl_xor(acce[j], mask);
            acce[j] = acce[j] * s1 + ao * s2;
        }
        m = mn;
    }
    if (qtr == 0) {
        float inv = 1.0f / (l + 1e-16f);
#pragma unroll
        for (int c = 0; c < CH; ++c) {
            float ec = 0.f;
#pragma unroll
            for (int j = 0; j < 8; ++j) ec += acce[j] * we_s[j * D + h * CH + c];
            float o = (accv[c] + ec) * inv + bf2f_(skp[(size_t)node * D + h * CH + c]);
            hout[(size_t)node * D + h * CH + c] = fmaxf(o, 0.f);
        }
    }
}

// ---------------- pooling (batch is sorted) ----------------
__global__ void k_pool(const float* __restrict__ h2, const int* __restrict__ batch,
                       float* __restrict__ pooled, float* __restrict__ cnt, int N) {
    int t = blockIdx.x * 256 + threadIdx.x;
    int start = t * 16;
    if (start >= N) return;
    int end = min(start + 16, N);
    float acc[20];
#pragma unroll
    for (int c = 0; c < 20; ++c) acc[c] = 0.f;
    int cg = batch[start];
    float run = 0.f;
    for (int n = start; n < end; ++n) {
        int g = batch[n];
        if (g != cg) {
#pragma unroll
            for (int c = 0; c < 20; ++c) atomicAdd(&pooled[cg * 20 + c], acc[c]);
            atomicAdd(&cnt[cg], run);
#pragma unroll
            for (int c = 0; c < 20; ++c) acc[c] = 0.f;
            run = 0.f;
            cg = g;
        }
#pragma unroll
        for (int c = 0; c < 20; ++c) acc[c] += h2[(size_t)n * 20 + c];
        run += 1.f;
    }
#pragma unroll
    for (int c = 0; c < 20; ++c) atomicAdd(&pooled[cg * 20 + c], acc[c]);
    atomicAdd(&cnt[cg], run);
}

__global__ void k_mlp(const float* __restrict__ pooled, const float* __restrict__ cnt,
                      const float* __restrict__ W1, const float* __restrict__ b1,
                      const float* __restrict__ W2, const float* __restrict__ b2,
                      float* __restrict__ out) {
    int g = threadIdx.x;
    if (g >= 64) return;
    float ic = 1.0f / fmaxf(cnt[g], 1.0f);
    float p[20];
#pragma unroll
    for (int i = 0; i < 20; ++i) p[i] = pooled[g * 20 + i] * ic;
    float hid[10];
#pragma unroll
    for (int j = 0; j < 10; ++j) {
        float a = b1[j];
#pragma unroll
        for (int i = 0; i < 20; ++i) a += p[i] * W1[i * 10 + j];
        hid[j] = fmaxf(a, 0.f);
    }
#pragma unroll
    for (int o = 0; o < 3; ++o) {
        float a = b2[o];
#pragma unroll
        for (int j = 0; j < 10; ++j) a += hid[j] * W2[j * 3 + o];
        out[g * 3 + o] = a;
    }
}

extern "C" void kernel_launch(void* const* d_in, const int* in_sizes, int n_in,
                              void* d_out, int out_size, void* d_ws, size_t ws_size,
                              hipStream_t stream) {
    const float* x   = (const float*)d_in[0];
    const int* ei    = (const int*)d_in[1];
    const float* ea  = (const float*)d_in[2];
    const int* batch = (const int*)d_in[3];
    const float *Wq1 = (const float*)d_in[4],  *bq1 = (const float*)d_in[5];
    const float *Wk1 = (const float*)d_in[6],  *bk1 = (const float*)d_in[7];
    const float *Wv1 = (const float*)d_in[8],  *bv1 = (const float*)d_in[9];
    const float *We1 = (const float*)d_in[10];
    const float *Ws1 = (const float*)d_in[11], *bs1 = (const float*)d_in[12];
    const float *Wq2 = (const float*)d_in[13], *bq2 = (const float*)d_in[14];
    const float *Wk2 = (const float*)d_in[15], *bk2 = (const float*)d_in[16];
    const float *Wv2 = (const float*)d_in[17], *bv2 = (const float*)d_in[18];
    const float *We2 = (const float*)d_in[19];
    const float *Ws2 = (const float*)d_in[20], *bs2 = (const float*)d_in[21];
    const float *W1  = (const float*)d_in[22], *b1  = (const float*)d_in[23];
    const float *W2  = (const float*)d_in[24], *b2  = (const float*)d_in[25];

    const int N = in_sizes[0] / 128;  // 100000
    const int E = in_sizes[1] / 2;    // 1600000
    const int* srcI = ei;
    const int* dstI = ei + E;

    // workspace layout (4B units), total ~96 MB
    float* F = (float*)d_ws;
    unsigned short* qbf = (unsigned short*)F;                // [N][4][16] bf16 (3.2M f)
    unsigned*       kv  = (unsigned*)(F + 3200000);          // [N][4][16] (6.4M u)
    float*          h1  = F + 9600000;                       // [N][40] f32 (4M)
    float*          h2  = F + 9600000;                       // alias h1
    unsigned short* s_bf = (unsigned short*)(F + 13600000);  // [N][40] bf16 (2M f)
    uint4*          eap = (uint4*)(F + 15600000);            // E x 16B (6.4M f)
    int*       src_perm = (int*)(F + 22000000);              // E x 4B (1.6M)
    int* I = (int*)(F + 23600000);
    int* deg  = I;                 // N (doubles as cur)
    int* cur  = I;
    int* rpR  = I + 100352;        // N+1
    int* bsum = I + 200704;        // 256
    short* wpackT = (short*)(F + 23900000);  // 160*136 bf16
    float* pooled = F + 23950000;  // 1280
    float* cnt    = pooled + 1280; // 64

    const int SCAN_BLOCKS = (N + 1023) / 1024;
    const int EB = (E + 255) / 256;

    hipMemsetAsync(deg, 0, (size_t)N * 4, stream);
    hipMemsetAsync(pooled, 0, (1280 + 64) * 4, stream);

    // W prep + CSR build (single-pass scatter, plain stores)
    k_wprep<<<(160 * 136 + 255) / 256, 256, 0, stream>>>(Wq1, Wk1, Wv1, Ws1, wpackT);
    k_hist<<<EB, 256, 0, stream>>>(dstI, deg, E);
    k_scan1<<<SCAN_BLOCKS, 256, 0, stream>>>(deg, rpR, bsum, N);
    k_scan2<<<1, 256, 0, stream>>>(bsum, SCAN_BLOCKS);
    k_scan3<<<SCAN_BLOCKS, 256, 0, stream>>>(rpR, bsum, cur, N, E);
    k_scatter<<<EB, 256, 0, stream>>>(srcI, dstI, rpR, cur, (const float4*)ea,
                                      src_perm, eap, E);

    // layer 1: MFMA projection; conv with line-aligned rows (KVP=QP=16)
    k_proj1m<<<(N + 63) / 64, 256, 0, stream>>>(x, wpackT, bq1, bk1, bv1, bs1,
                                                qbf, kv, s_bf, N);
    k_conv<10, 16, 16><<<(16 * N + 255) / 256, 256, 0, stream>>>(
        rpR, src_perm, eap, We1, qbf, kv, s_bf, h1, 0.31622776601683794f, N);

    // layer 2: 40 -> 4 heads x 5 (KVP=QP=8)
    k_proj<40, 5, 40, 1, 8, 8, 32><<<(N + 31) / 32, 256, 0, stream>>>(
        h1, Wq2, Wk2, Wv2, Ws2, bq2, bk2, bv2, bs2, qbf, kv, s_bf, N);
    k_conv<5, 8, 8><<<(16 * N + 255) / 256, 256, 0, stream>>>(
        rpR, src_perm, eap, We2, qbf, kv, s_bf, h2, 0.4472135954999579f, N);

    // pool + MLP
    k_pool<<<((N + 15) / 16 + 255) / 256, 256, 0, stream>>>(h2, batch, pooled, cnt, N);
    k_mlp<<<1, 64, 0, stream>>>(pooled, cnt, W1, b1, W2, b2, (float*)d_out);
}